// Round 5
// baseline (737.232 us; speedup 1.0000x reference)
//
#include <hip/hip_runtime.h>

// RelativePosition: out[b,i,j,:] = (W[clip(ri[b,j]-ri[b,i],-32,32)+33] + bias) * (m[b,i]*m[b,j])
// B=2, L=768, C_Z=128. Output 604 MB f32 -> store-BW bound (~96 us @ 6.3 TB/s).
//
// R5 = DIAGNOSTIC: identical kernel to R4, launched TWICE (idempotent writes).
// dur_us(R5) - dur_us(R4) = true kernel duration, invisible in rocprof top-5
// (harness poison fills at ~383 us dominate the table). Resolves whether the
// kernel is ~130 us (near 96 us floor -> roofline) or ~217 us (headroom).

constexpr int BINS = 32;
constexpr int CZ   = 128;
constexpr int NC   = 2 * BINS + 2;   // 66
constexpr int B_   = 2;
constexpr int L_   = 768;
constexpr int ROWS_PER_BLOCK = 2;
constexpr int NBLK = B_ * L_ / ROWS_PER_BLOCK;  // 768

typedef float vfloat4 __attribute__((ext_vector_type(4)));

__global__ __launch_bounds__(256) void relpos_kernel(
    const int*  __restrict__ residue_index,   // [B,L] int32
    const void* __restrict__ residue_mask,    // [B,L] bool (byte or int32 layout, detected)
    const float* __restrict__ W,              // [NC, CZ]
    const float* __restrict__ bias,           // [CZ]
    float* __restrict__ out)                  // [B,L,L,CZ]
{
    __shared__ float wb[NC * CZ];             // 33 KB: W + bias
    __shared__ int   ridx_row[L_];            // 3 KB
    __shared__ float mask_row[L_];            // 3 KB
    __shared__ int   s_cnt[2 * ROWS_PER_BLOCK];  // {jlo, jend} per row

    const int tid  = threadIdx.x;
    const int row0 = blockIdx.x * ROWS_PER_BLOCK;  // both rows in same batch (L even)
    const int b    = row0 / L_;
    const int o    = b * L_;

    // Detect mask layout (wave-uniform, L2-cached).
    const unsigned int v0 = *(const unsigned int*)residue_mask;
    const bool byte_layout = (v0 & 0xFFFFFF00u) != 0u;

    // Stage Wb = W + bias (2112 float4s) and this batch's index/mask row.
    const vfloat4* W4  = (const vfloat4*)W;
    const vfloat4* bi4 = (const vfloat4*)bias;
    vfloat4* wb4 = (vfloat4*)wb;
    for (int k = tid; k < NC * CZ / 4; k += 256)
        wb4[k] = W4[k] + bi4[k & (CZ / 4 - 1)];
    for (int k = tid; k < L_; k += 256) {
        ridx_row[k] = residue_index[o + k];
        int m = byte_layout ? (int)((const unsigned char*)residue_mask)[o + k]
                            : ((const int*)residue_mask)[o + k];
        mask_row[k] = m ? 1.0f : 0.0f;
    }
    if (tid < 2 * ROWS_PER_BLOCK) s_cnt[tid] = 0;
    __syncthreads();

    // Region boundaries per row (diff is monotone non-decreasing in j):
    //   jlo  = #{j : diff <= -BINS}  -> j <  jlo  : idx==1  (vlo)
    //   jend = #{j : diff <   BINS}  -> j >= jend : idx==65 (vhi)
    for (int r = 0; r < ROWS_PER_BLOCK; ++r) {
        const int ri_i = ridx_row[row0 - o + r];
        int c1 = 0, c2 = 0;
        for (int j = tid; j < L_; j += 256) {
            const int diff = ridx_row[j] - ri_i;
            c1 += (diff <= -BINS);
            c2 += (diff <   BINS);
        }
        atomicAdd(&s_cnt[2 * r + 0], c1);
        atomicAdd(&s_cnt[2 * r + 1], c2);
    }
    __syncthreads();

    const int group = tid >> 5;   // 0..7: one 32-lane group per (i,j) pair
    const int lane  = tid & 31;   // 16 B per lane -> 512 B per pair
    const vfloat4 vlo = ((const vfloat4*)(wb + 1 * CZ))[lane];        // idx==1
    const vfloat4 vhi = ((const vfloat4*)(wb + (NC - 1) * CZ))[lane]; // idx==65

    for (int r = 0; r < ROWS_PER_BLOCK; ++r) {
        const int   i    = row0 - o + r;
        const int   ri_i = ridx_row[i];
        const float m_i  = mask_row[i];
        const int   jlo  = s_cnt[2 * r + 0];
        const int   jend = s_cnt[2 * r + 1];
        float* rowout = out + (size_t)(row0 + r) * L_ * CZ;

        // Low saturated stream: constant vlo, no table lookup.
        #pragma unroll 4
        for (int j = group; j < jlo; j += 8) {
            vfloat4 v = vlo * (m_i * mask_row[j]);
            ((vfloat4*)(rowout + j * CZ))[lane] = v;
        }
        // Band: general gather (short: ~2*BINS/avg_gap iterations).
        for (int j = jlo + group; j < jend; j += 8) {
            const int diff = ridx_row[j] - ri_i;
            const int idx  = min(max(diff, -BINS), BINS) + BINS + 1;
            vfloat4 v = ((const vfloat4*)(wb + idx * CZ))[lane];
            v *= m_i * mask_row[j];
            ((vfloat4*)(rowout + j * CZ))[lane] = v;
        }
        // High saturated stream: constant vhi.
        #pragma unroll 4
        for (int j = jend + ((group - jend) & 7); j < L_; j += 8) {
            vfloat4 v = vhi * (m_i * mask_row[j]);
            ((vfloat4*)(rowout + j * CZ))[lane] = v;
        }
    }
}

extern "C" void kernel_launch(void* const* d_in, const int* in_sizes, int n_in,
                              void* d_out, int out_size, void* d_ws, size_t ws_size,
                              hipStream_t stream) {
    const int*  residue_index = (const int*)d_in[0];
    const void* residue_mask  = d_in[1];
    const float* W    = (const float*)d_in[2];
    const float* bias = (const float*)d_in[3];
    float* out = (float*)d_out;

    // DIAGNOSTIC double-launch: identical idempotent work; the dur_us delta vs
    // the single-launch round is the kernel's true duration.
    relpos_kernel<<<NBLK, 256, 0, stream>>>(residue_index, residue_mask, W, bias, out);
    relpos_kernel<<<NBLK, 256, 0, stream>>>(residue_index, residue_mask, W, bias, out);
}

// Round 6
// 598.616 us; speedup vs baseline: 1.2316x; 1.2316x over previous
//
#include <hip/hip_runtime.h>

// RelativePosition: out[b,i,j,:] = (W[clip(ri[b,j]-ri[b,i],-32,32)+33] + bias) * (m[b,i]*m[b,j])
// B=2, L=768, C_Z=128. Output 604 MB f32 -> store-BW bound (~96 us @ 6.3 TB/s).
//
// R5 diagnostic: true kernel time = 128 us (4.7 TB/s); harness fixed cost ~480 us.
// R6: close the 128->96 gap. (1) drop the 33 KB wb LDS table (vlo/vhi in regs,
// band gathers W from L2), LDS 40->6 KB; (2) per-row all-ones-mask fast path:
// saturated streams are pure register-constant store loops (fillBuffer-shaped,
// zero loads, unroll 8); (3) 1 row/block -> 1536 blocks -> 24 waves/CU.

constexpr int BINS = 32;
constexpr int CZ   = 128;
constexpr int NC   = 2 * BINS + 2;   // 66
constexpr int B_   = 2;
constexpr int L_   = 768;
constexpr int NBLK = B_ * L_;        // 1536: one block per output row [b,i]

typedef float vfloat4 __attribute__((ext_vector_type(4)));

__global__ __launch_bounds__(256) void relpos_kernel(
    const int*  __restrict__ residue_index,   // [B,L] int32
    const void* __restrict__ residue_mask,    // [B,L] bool (byte or int32 layout, detected)
    const float* __restrict__ W,              // [NC, CZ]
    const float* __restrict__ bias,           // [CZ]
    float* __restrict__ out)                  // [B,L,L,CZ]
{
    __shared__ int   ridx_row[L_];    // 3 KB
    __shared__ float mask_row[L_];    // 3 KB
    __shared__ int   s_cnt[3];        // jlo, jend, #mask-ones

    const int tid = threadIdx.x;
    const int row = blockIdx.x;       // b*L + i
    const int b   = row / L_;
    const int i   = row - b * L_;
    const int o   = b * L_;

    const int group = tid >> 5;       // 0..7: one 32-lane group per (i,j) pair
    const int lane  = tid & 31;       // 16 B per lane -> 512 B per pair

    // Detect mask layout (wave-uniform, L2-cached).
    const unsigned int v0 = *(const unsigned int*)residue_mask;
    const bool byte_layout = (v0 & 0xFFFFFF00u) != 0u;

    // Saturated-row values straight from global (L2-hot, once per block).
    const vfloat4* W4 = (const vfloat4*)W;
    const vfloat4 b4  = ((const vfloat4*)bias)[lane];
    const vfloat4 vlo = W4[1 * (CZ / 4) + lane] + b4;         // idx==1
    const vfloat4 vhi = W4[(NC - 1) * (CZ / 4) + lane] + b4;  // idx==65

    if (tid < 3) s_cnt[tid] = 0;
    for (int k = tid; k < L_; k += 256) {
        ridx_row[k] = residue_index[o + k];
        int m = byte_layout ? (int)((const unsigned char*)residue_mask)[o + k]
                            : ((const int*)residue_mask)[o + k];
        mask_row[k] = m ? 1.0f : 0.0f;
    }
    __syncthreads();

    const int   ri_i = ridx_row[i];
    const float m_i  = mask_row[i];

    // Region boundaries (diff monotone non-decreasing in j) + mask-ones count:
    //   jlo  = #{j : diff <= -BINS}  -> j <  jlo  : idx==1  (vlo)
    //   jend = #{j : diff <   BINS}  -> j >= jend : idx==65 (vhi)
    {
        int c1 = 0, c2 = 0, cm = 0;
        for (int j = tid; j < L_; j += 256) {
            const int diff = ridx_row[j] - ri_i;
            c1 += (diff <= -BINS);
            c2 += (diff <   BINS);
            cm += (mask_row[j] != 0.0f);
        }
        for (int off = 32; off; off >>= 1) {   // wave64 reduce -> 1 atomic set/wave
            c1 += __shfl_down(c1, off);
            c2 += __shfl_down(c2, off);
            cm += __shfl_down(cm, off);
        }
        if ((tid & 63) == 0) {
            atomicAdd(&s_cnt[0], c1);
            atomicAdd(&s_cnt[1], c2);
            atomicAdd(&s_cnt[2], cm);
        }
    }
    __syncthreads();

    const int  jlo  = s_cnt[0];
    const int  jend = s_cnt[1];
    const bool fast = (s_cnt[2] == L_) && (m_i == 1.0f);  // all masks == 1

    float* rowout = out + (size_t)row * L_ * CZ;   // contiguous 384 KB row
    // Group g handles j == g (mod 8) in every region -> a wave's two groups
    // always write adjacent j's = 1 KB contiguous per wave store-pair.
    const int jb0 = jlo  + ((group - jlo ) & 7);
    const int jh0 = jend + ((group - jend) & 7);

    if (fast) {
        // Pure register-constant store streams: no loads in the loop at all.
        #pragma unroll 8
        for (int j = group; j < jlo; j += 8)
            ((vfloat4*)(rowout + j * CZ))[lane] = vlo;
        #pragma unroll 2
        for (int j = jb0; j < jend; j += 8) {      // band: ~48 j's per row
            const int diff = ridx_row[j] - ri_i;
            const int idx  = min(max(diff, -BINS), BINS) + BINS + 1;
            ((vfloat4*)(rowout + j * CZ))[lane] = W4[idx * (CZ / 4) + lane] + b4;
        }
        #pragma unroll 8
        for (int j = jh0; j < L_; j += 8)
            ((vfloat4*)(rowout + j * CZ))[lane] = vhi;
    } else {
        // General path: per-j mask product.
        #pragma unroll 4
        for (int j = group; j < jlo; j += 8)
            ((vfloat4*)(rowout + j * CZ))[lane] = vlo * (m_i * mask_row[j]);
        #pragma unroll 2
        for (int j = jb0; j < jend; j += 8) {
            const int diff = ridx_row[j] - ri_i;
            const int idx  = min(max(diff, -BINS), BINS) + BINS + 1;
            vfloat4 v = W4[idx * (CZ / 4) + lane] + b4;
            ((vfloat4*)(rowout + j * CZ))[lane] = v * (m_i * mask_row[j]);
        }
        #pragma unroll 4
        for (int j = jh0; j < L_; j += 8)
            ((vfloat4*)(rowout + j * CZ))[lane] = vhi * (m_i * mask_row[j]);
    }
}

extern "C" void kernel_launch(void* const* d_in, const int* in_sizes, int n_in,
                              void* d_out, int out_size, void* d_ws, size_t ws_size,
                              hipStream_t stream) {
    const int*  residue_index = (const int*)d_in[0];
    const void* residue_mask  = d_in[1];
    const float* W    = (const float*)d_in[2];
    const float* bias = (const float*)d_in[3];
    float* out = (float*)d_out;

    relpos_kernel<<<NBLK, 256, 0, stream>>>(residue_index, residue_mask, W, bias, out);
}